// Round 14
// baseline (149.333 us; speedup 1.0000x reference)
//
#include <hip/hip_runtime.h>
#include <hip/hip_bf16.h>

#define NPAIR 136
#define NH 68          // pairs per half (136 = 2*68)
#define NOUT 17408     // NH * 256 threads
#define NBLK 512       // fused grid: 32 clouds/block
#define NCHUNK 8       // reduce1 chunks (NBLK/64)

using frag8 = __attribute__((ext_vector_type(8))) short;
using f32x4 = __attribute__((ext_vector_type(4))) float;
using i32x4 = __attribute__((ext_vector_type(4))) int;
using u16x8 = __attribute__((ext_vector_type(8))) unsigned short;

// Pack two f32 -> bf16x2 by truncation with ONE v_perm_b32.
__device__ inline int pack_bf16(float lo, float hi){
  unsigned a, b;
  __builtin_memcpy(&a, &hi, 4);
  __builtin_memcpy(&b, &lo, 4);
  return (int)__builtin_amdgcn_perm(a, b, 0x07060302u);
}

__device__ inline float bf2f(unsigned short v){
  unsigned u32 = ((unsigned)v) << 16;
  float f; __builtin_memcpy(&f, &u32, 4);
  return f;
}

struct PairTab { int pi[NPAIR]; int pj[NPAIR]; };
constexpr PairTab make_pairs(){
  PairTab t{}; int u = 0;
  for (int i = 0; i < 16; ++i) for (int j = i; j < 16; ++j){ t.pi[u]=i; t.pj[u]=j; ++u; }
  return t;
}
constexpr PairTab PT = make_pairs();

// Consumer: accumulate 68 pair-products for feature f over 8 clouds in cb.
// cb layout: [cloud 0..7][row 0..15][f 0..127] bf16, byte ^= ((row&7)<<4) swizzle.
template<int H>
__device__ inline void cell_accum(const char* cb, int f, float (&cacc)[NH]){
#pragma unroll
  for (int c = 0; c < 8; ++c){
    float z[16];
#pragma unroll
    for (int rr = 0; rr < 16; ++rr){
      int byte = ((c*16 + rr)*256 + f*2) ^ ((rr & 7) << 4);
      unsigned short v = *reinterpret_cast<const unsigned short*>(cb + byte);
      z[rr] = bf2f(v);
    }
#pragma unroll
    for (int u = 0; u < NH; ++u)      // compile-time pair indices -> all regs
      cacc[u] = fmaf(z[PT.pi[H*NH+u]], z[PT.pj[H*NH+u]], cacc[u]);
  }
}

// ---- inline-asm streaming: compiler-invisible loads + hand-counted vmcnt ----
// Two dwordx4 per kk at byte offsets kk*128 and kk*128+16 from per-lane addr pp.
#define ISSUE(OFF0, OFF1, D0, D1) \
  asm volatile("global_load_dwordx4 %0, %2, off offset:" OFF0 "\n\t" \
               "global_load_dwordx4 %1, %2, off offset:" OFF1 \
               : "=&v"(D0), "=&v"(D1) : "v"(pp));

#define WAITC(N) \
  asm volatile("s_waitcnt vmcnt(" #N ")"); \
  __builtin_amdgcn_sched_barrier(0);

#define CONSUME(KK, D0, D1) { \
  i32x4 fi; \
  fi[0] = pack_bf16((D0).x, (D0).y); fi[1] = pack_bf16((D0).z, (D0).w); \
  fi[2] = pack_bf16((D1).x, (D1).y); fi[3] = pack_bf16((D1).z, (D1).w); \
  if ((KK) >= 12){ \
    int byte_ = ((ci*16 + r)*256 + ((KK)-12)*64 + g*16) ^ ((r & 7) << 4); \
    *reinterpret_cast<i32x4*>(cb + byte_) = fi; } \
  frag8 fr = __builtin_bit_cast(frag8, fi); \
  if ((KK) & 1) acc1 = __builtin_amdgcn_mfma_f32_16x16x32_bf16(fr, fr, acc1, 0, 0, 0); \
  else          acc0 = __builtin_amdgcn_mfma_f32_16x16x32_bf16(fr, fr, acc0, 0, 0, 0); }

// ---- fused: gene Gram via MFMA + cell Gram from the same loaded data ----
__global__ __launch_bounds__(256) void fused_kernel(const float* __restrict__ X,
                                                    const float* __restrict__ Y,
                                                    unsigned short* __restrict__ cell_partials,
                                                    float* __restrict__ gene_part){
  __shared__ char cellbuf[65536];      // 2 x (8 clouds x 16 rows x 128 f bf16)
  const int t = threadIdx.x;
  const int wave = t >> 6, lane = t & 63;
  const int r = lane & 15;             // row of Z (0-7 = X, 8-15 = Y)
  const int g = lane >> 4;             // k-group
  const int f = t & 127;               // cell feature
  const int h = t >> 7;                // pair-half 0/1 (wave-uniform)

  float cacc[NH];
#pragma unroll
  for (int u = 0; u < NH; ++u) cacc[u] = 0.f;
  float gene_acc = 0.f;

  const int cbase = blockIdx.x * 32;   // 32 clouds per block: 4 passes x 8 clouds
  for (int pass = 0; pass < 4; ++pass){
    char* cb = cellbuf + (pass & 1)*32768;
#pragma unroll
    for (int sub = 0; sub < 2; ++sub){
      const int ci = sub*4 + wave;                  // cloud slot 0..7 in this pass
      const int b = cbase + pass*8 + ci;
      const float* base = (r < 8) ? X + (size_t)b*4096 + (size_t)r*512
                                  : Y + (size_t)b*4096 + (size_t)(r-8)*512;
      const float* pp = base + g*8;                 // per-lane stream base
      f32x4 acc0 = {0.f,0.f,0.f,0.f}, acc1 = {0.f,0.f,0.f,0.f};
      float4 B0,B1,B2,B3,B4,B5,B6,B7,B8,B9,B10,B11,B12,B13,B14,B15;
      // prologue: 16 loads (kk 0..7) in flight
      ISSUE("0",   "16",  B0, B1)
      ISSUE("128", "144", B2, B3)
      ISSUE("256", "272", B4, B5)
      ISSUE("384", "400", B6, B7)
      ISSUE("512", "528", B8, B9)
      ISSUE("640", "656", B10,B11)
      ISSUE("768", "784", B12,B13)
      ISSUE("896", "912", B14,B15)
      // steady state: consume kk, reissue kk+8 into the freed pair
      WAITC(14) CONSUME(0, B0, B1)  ISSUE("1024","1040",B0, B1)
      WAITC(14) CONSUME(1, B2, B3)  ISSUE("1152","1168",B2, B3)
      WAITC(14) CONSUME(2, B4, B5)  ISSUE("1280","1296",B4, B5)
      WAITC(14) CONSUME(3, B6, B7)  ISSUE("1408","1424",B6, B7)
      WAITC(14) CONSUME(4, B8, B9)  ISSUE("1536","1552",B8, B9)
      WAITC(14) CONSUME(5, B10,B11) ISSUE("1664","1680",B10,B11)
      WAITC(14) CONSUME(6, B12,B13) ISSUE("1792","1808",B12,B13)
      WAITC(14) CONSUME(7, B14,B15) ISSUE("1920","1936",B14,B15)
      // drain
      WAITC(14) CONSUME(8,  B0, B1)
      WAITC(12) CONSUME(9,  B2, B3)
      WAITC(10) CONSUME(10, B4, B5)
      WAITC(8)  CONSUME(11, B6, B7)
      WAITC(6)  CONSUME(12, B8, B9)
      WAITC(4)  CONSUME(13, B10,B11)
      WAITC(2)  CONSUME(14, B12,B13)
      WAITC(0)  CONSUME(15, B14,B15)
      f32x4 acc = acc0 + acc1;
      // diag exchange, wave-private via bpermute (r8/r9-verified):
      // diag[d] lives in lane d+16*(d>>2), register acc[d&3].
      float mydiag = acc[0];
      mydiag = ((r & 3) == 1) ? acc[1] : mydiag;
      mydiag = ((r & 3) == 2) ? acc[2] : mydiag;
      mydiag = ((r & 3) == 3) ? acc[3] : mydiag;
      int md = __builtin_bit_cast(int, mydiag);
      float dcol = __builtin_bit_cast(float,
          __builtin_amdgcn_ds_bpermute(4*(r + 16*(r >> 2)), md));
      float sc = 0.f;
#pragma unroll
      for (int qq = 0; qq < 4; ++qq){
        float drow = __builtin_bit_cast(float,
            __builtin_amdgcn_ds_bpermute(4*(20*g + qq), md));
        int row = g*4 + qq;
        float sqd = drow + dcol - 2.f*acc[qq];
        float dist = sqrtf(fmaxf(sqd, 0.f));
        sc += (((row < 8) == (r < 8)) ? -dist : dist);
      }
      gene_acc += sc;
    }
    __syncthreads();                   // cellbuf half ready (only barrier per pass)
    if (h == 0) cell_accum<0>(cb, f, cacc);
    else        cell_accum<1>(cb, f, cacc);
    // no trailing barrier: pass p+2's writes to this half are ordered by
    // pass p+1's barrier (every thread consumed this half before reaching it)
  }
  // gene reduction: per-wave shuffle, one entry per wave
#pragma unroll
  for (int off = 32; off > 0; off >>= 1) gene_acc += __shfl_xor(gene_acc, off);
  if (lane == 0) gene_part[blockIdx.x*4 + wave] = gene_acc * (1.f/128.f);
  // cell partials in bf16 (coalesced across t)
  unsigned short* dst = cell_partials + (size_t)blockIdx.x * NOUT;
#pragma unroll
  for (int u = 0; u < NH; ++u){
    __hip_bfloat16 bv = __float2bfloat16(cacc[u]);   // RNE
    unsigned short sv; __builtin_memcpy(&sv, &bv, 2);
    dst[u*256 + t] = sv;
  }
}

// Vectorized reduce1: thread owns 8 consecutive outputs (ushort8 = 16B loads,
// contiguous 2KB/instr across a block) over a 64-deep p-chunk; coalesced
// 32B float stores to partial2. Deterministic (no atomics, no memset).
__global__ __launch_bounds__(128) void reduce1_kernel(const unsigned short* __restrict__ partials,
                                                      float* __restrict__ partial2){
  const int s = blockIdx.x % 17;                 // o-slice: 17*128*8 = NOUT
  const int c = blockIdx.x / 17;                 // p-chunk (NCHUNK chunks of 64)
  const int o = (s*128 + threadIdx.x) * 8;
  const int p0 = c*64;
  float acc[8];
#pragma unroll
  for (int k = 0; k < 8; ++k) acc[k] = 0.f;
  for (int p = p0; p < p0 + 64; ++p){
    u16x8 v = *reinterpret_cast<const u16x8*>(partials + (size_t)p*NOUT + o);
#pragma unroll
    for (int k = 0; k < 8; ++k) acc[k] += bf2f(v[k]);
  }
#pragma unroll
  for (int k = 0; k < 8; ++k) partial2[(size_t)c*NOUT + o + k] = acc[k];
}

// Parallel 557KB -> 68KB reduction (68 blocks).
__global__ __launch_bounds__(256) void reduce2_kernel(const float* __restrict__ partial2,
                                                      float* __restrict__ G){
  int o = blockIdx.x*256 + threadIdx.x;          // grid 68
  float s = 0.f;
#pragma unroll
  for (int c = 0; c < NCHUNK; ++c) s += partial2[(size_t)c*NOUT + o];
  G[o] = s;
}

__device__ inline float getGs(const float* Gs, int f, int i, int j){
  int a = i < j ? i : j, c = i < j ? j : i;
  int k = a*16 - (a*(a-1))/2 + (c - a);          // linear index of (a,c), a<=c
  int hh = (k >= NH) ? 1 : 0;
  int u = k - hh*NH;
  return Gs[u*256 + hh*128 + f];
}

__global__ __launch_bounds__(256) void final_kernel(const float* __restrict__ G,
                                                    const float* __restrict__ gene_part,
                                                    int ngp, float* __restrict__ out){
  __shared__ float Gs[NOUT];           // 69.6 KB, loaded from 68KB Gbuf
  __shared__ float red[256];
  int t = threadIdx.x;
#pragma unroll
  for (int k = 0; k < NH; ++k) Gs[k*256 + t] = G[k*256 + t];
  __syncthreads();
  float v = 0.f;
  if (t < 128){
    int f = t;
    float d[16];
#pragma unroll
    for (int i = 0; i < 16; ++i) d[i] = getGs(Gs, f, i, i);
    float sum = 0.f;
#pragma unroll
    for (int i = 0; i < 16; ++i){
#pragma unroll
      for (int j = 0; j < 16; ++j){
        float sqd = d[i] + d[j] - 2.f*getGs(Gs, f, i, j);
        float dist = sqrtf(fmaxf(sqd, 0.f));
        sum += (((i < 8) == (j < 8)) ? -dist : dist);
      }
    }
    v = sum * (1.f/128.f) * (1.f/128.f);         // per-feature value / 128 features
  }
  float gp = 0.f;
  for (int idx = t; idx < ngp; idx += 256) gp += gene_part[idx];
  v += gp * (1.f/16384.f);                       // mean over clouds
  red[t] = v;
  __syncthreads();
  for (int s2 = 128; s2 > 0; s2 >>= 1){
    if (t < s2) red[t] += red[t + s2];
    __syncthreads();
  }
  if (t == 0) out[0] = red[0];
}

extern "C" void kernel_launch(void* const* d_in, const int* in_sizes, int n_in,
                              void* d_out, int out_size, void* d_ws, size_t ws_size,
                              hipStream_t stream){
  const float* X = (const float*)d_in[0];
  const float* Y = (const float*)d_in[1];
  float* out = (float*)d_out;

  float* wsf       = (float*)d_ws;
  float* gene_part = wsf;                            // NBLK*4 = 2048 floats
  float* Gbuf      = wsf + 2048;                     // NOUT floats
  float* partial2  = wsf + 2048 + NOUT;              // NCHUNK*NOUT floats
  unsigned short* partials =
      (unsigned short*)(wsf + 2048 + (1+NCHUNK)*NOUT);  // NBLK*NOUT bf16 (~17.8 MB)

  fused_kernel<<<NBLK, 256, 0, stream>>>(X, Y, partials, gene_part);
  reduce1_kernel<<<17*NCHUNK, 128, 0, stream>>>(partials, partial2);
  reduce2_kernel<<<68, 256, 0, stream>>>(partial2, Gbuf);
  final_kernel<<<1, 256, 0, stream>>>(Gbuf, gene_part, 4*NBLK, out);
}

// Round 15
// 128.335 us; speedup vs baseline: 1.1636x; 1.1636x over previous
//
#include <hip/hip_runtime.h>
#include <hip/hip_bf16.h>

#define NPAIR 136
#define NH 68          // pairs per half (136 = 2*68)
#define NOUT 17408     // NH * 256 threads
#define NBLK 512       // fused grid: 32 clouds/block
#define NCHUNK 8       // reduce1 chunks (NBLK/64)

using frag8 = __attribute__((ext_vector_type(8))) short;
using f32x4 = __attribute__((ext_vector_type(4))) float;
using i32x4 = __attribute__((ext_vector_type(4))) int;

// Pack two f32 -> bf16x2 by truncation with ONE v_perm_b32.
__device__ inline int pack_bf16(float lo, float hi){
  unsigned a, b;
  __builtin_memcpy(&a, &hi, 4);
  __builtin_memcpy(&b, &lo, 4);
  return (int)__builtin_amdgcn_perm(a, b, 0x07060302u);
}

__device__ inline float bf2f(unsigned short v){
  unsigned u32 = ((unsigned)v) << 16;
  float f; __builtin_memcpy(&f, &u32, 4);
  return f;
}

struct PairTab { int pi[NPAIR]; int pj[NPAIR]; };
constexpr PairTab make_pairs(){
  PairTab t{}; int u = 0;
  for (int i = 0; i < 16; ++i) for (int j = i; j < 16; ++j){ t.pi[u]=i; t.pj[u]=j; ++u; }
  return t;
}
constexpr PairTab PT = make_pairs();

// Consumer: accumulate 68 pair-products for feature f over 8 clouds in cb.
// cb layout: [cloud 0..7][row 0..15][f 0..127] bf16, byte ^= ((row&7)<<4) swizzle.
template<int H>
__device__ inline void cell_accum(const char* cb, int f, float (&cacc)[NH]){
#pragma unroll
  for (int c = 0; c < 8; ++c){
    float z[16];
#pragma unroll
    for (int rr = 0; rr < 16; ++rr){
      int byte = ((c*16 + rr)*256 + f*2) ^ ((rr & 7) << 4);
      unsigned short v = *reinterpret_cast<const unsigned short*>(cb + byte);
      z[rr] = bf2f(v);
    }
#pragma unroll
    for (int u = 0; u < NH; ++u)      // compile-time pair indices -> all regs
      cacc[u] = fmaf(z[PT.pi[H*NH+u]], z[PT.pj[H*NH+u]], cacc[u]);
  }
}

// ---- inline-asm streaming: compiler-invisible loads + hand-counted vmcnt ----
// Two dwordx4 per kk at byte offsets kk*128 and kk*128+16 from per-lane addr pp.
#define ISSUE(OFF0, OFF1, D0, D1) \
  asm volatile("global_load_dwordx4 %0, %2, off offset:" OFF0 "\n\t" \
               "global_load_dwordx4 %1, %2, off offset:" OFF1 \
               : "=&v"(D0), "=&v"(D1) : "v"(pp));

#define WAITC(N) \
  asm volatile("s_waitcnt vmcnt(" #N ")"); \
  __builtin_amdgcn_sched_barrier(0);

#define CONSUME(KK, D0, D1) { \
  i32x4 fi; \
  fi[0] = pack_bf16((D0).x, (D0).y); fi[1] = pack_bf16((D0).z, (D0).w); \
  fi[2] = pack_bf16((D1).x, (D1).y); fi[3] = pack_bf16((D1).z, (D1).w); \
  if ((KK) >= 12){ \
    int byte_ = ((ci*16 + r)*256 + ((KK)-12)*64 + g*16) ^ ((r & 7) << 4); \
    *reinterpret_cast<i32x4*>(cb + byte_) = fi; } \
  frag8 fr = __builtin_bit_cast(frag8, fi); \
  if ((KK) & 1) acc1 = __builtin_amdgcn_mfma_f32_16x16x32_bf16(fr, fr, acc1, 0, 0, 0); \
  else          acc0 = __builtin_amdgcn_mfma_f32_16x16x32_bf16(fr, fr, acc0, 0, 0, 0); }

// ---- fused: gene Gram via MFMA + cell Gram from the same loaded data ----
__global__ __launch_bounds__(256) void fused_kernel(const float* __restrict__ X,
                                                    const float* __restrict__ Y,
                                                    unsigned short* __restrict__ cell_partials,
                                                    float* __restrict__ gene_part){
  __shared__ char cellbuf[65536];      // 2 x (8 clouds x 16 rows x 128 f bf16)
  const int t = threadIdx.x;
  const int wave = t >> 6, lane = t & 63;
  const int r = lane & 15;             // row of Z (0-7 = X, 8-15 = Y)
  const int g = lane >> 4;             // k-group
  const int f = t & 127;               // cell feature
  const int h = t >> 7;                // pair-half 0/1 (wave-uniform)

  float cacc[NH];
#pragma unroll
  for (int u = 0; u < NH; ++u) cacc[u] = 0.f;
  float gene_acc = 0.f;

  const int cbase = blockIdx.x * 32;   // 32 clouds per block: 4 passes x 8 clouds
  for (int pass = 0; pass < 4; ++pass){
    char* cb = cellbuf + (pass & 1)*32768;
#pragma unroll
    for (int sub = 0; sub < 2; ++sub){
      const int ci = sub*4 + wave;                  // cloud slot 0..7 in this pass
      const int b = cbase + pass*8 + ci;
      const float* base = (r < 8) ? X + (size_t)b*4096 + (size_t)r*512
                                  : Y + (size_t)b*4096 + (size_t)(r-8)*512;
      const float* pp = base + g*8;                 // per-lane stream base
      f32x4 acc0 = {0.f,0.f,0.f,0.f}, acc1 = {0.f,0.f,0.f,0.f};
      float4 B0,B1,B2,B3,B4,B5,B6,B7,B8,B9,B10,B11,B12,B13,B14,B15;
      // prologue: 16 loads (kk 0..7) in flight
      ISSUE("0",   "16",  B0, B1)
      ISSUE("128", "144", B2, B3)
      ISSUE("256", "272", B4, B5)
      ISSUE("384", "400", B6, B7)
      ISSUE("512", "528", B8, B9)
      ISSUE("640", "656", B10,B11)
      ISSUE("768", "784", B12,B13)
      ISSUE("896", "912", B14,B15)
      // steady state: consume kk, reissue kk+8 into the freed pair
      WAITC(14) CONSUME(0, B0, B1)  ISSUE("1024","1040",B0, B1)
      WAITC(14) CONSUME(1, B2, B3)  ISSUE("1152","1168",B2, B3)
      WAITC(14) CONSUME(2, B4, B5)  ISSUE("1280","1296",B4, B5)
      WAITC(14) CONSUME(3, B6, B7)  ISSUE("1408","1424",B6, B7)
      WAITC(14) CONSUME(4, B8, B9)  ISSUE("1536","1552",B8, B9)
      WAITC(14) CONSUME(5, B10,B11) ISSUE("1664","1680",B10,B11)
      WAITC(14) CONSUME(6, B12,B13) ISSUE("1792","1808",B12,B13)
      WAITC(14) CONSUME(7, B14,B15) ISSUE("1920","1936",B14,B15)
      // drain
      WAITC(14) CONSUME(8,  B0, B1)
      WAITC(12) CONSUME(9,  B2, B3)
      WAITC(10) CONSUME(10, B4, B5)
      WAITC(8)  CONSUME(11, B6, B7)
      WAITC(6)  CONSUME(12, B8, B9)
      WAITC(4)  CONSUME(13, B10,B11)
      WAITC(2)  CONSUME(14, B12,B13)
      WAITC(0)  CONSUME(15, B14,B15)
      f32x4 acc = acc0 + acc1;
      // diag exchange, wave-private via bpermute (r8/r9-verified):
      // diag[d] lives in lane d+16*(d>>2), register acc[d&3].
      float mydiag = acc[0];
      mydiag = ((r & 3) == 1) ? acc[1] : mydiag;
      mydiag = ((r & 3) == 2) ? acc[2] : mydiag;
      mydiag = ((r & 3) == 3) ? acc[3] : mydiag;
      int md = __builtin_bit_cast(int, mydiag);
      float dcol = __builtin_bit_cast(float,
          __builtin_amdgcn_ds_bpermute(4*(r + 16*(r >> 2)), md));
      float sc = 0.f;
#pragma unroll
      for (int qq = 0; qq < 4; ++qq){
        float drow = __builtin_bit_cast(float,
            __builtin_amdgcn_ds_bpermute(4*(20*g + qq), md));
        int row = g*4 + qq;
        float sqd = drow + dcol - 2.f*acc[qq];
        float dist = sqrtf(fmaxf(sqd, 0.f));
        sc += (((row < 8) == (r < 8)) ? -dist : dist);
      }
      gene_acc += sc;
    }
    __syncthreads();                   // cellbuf half ready (only barrier per pass)
    if (h == 0) cell_accum<0>(cb, f, cacc);
    else        cell_accum<1>(cb, f, cacc);
    // no trailing barrier: pass p+2's writes to this half are ordered by
    // pass p+1's barrier (every thread consumed this half before reaching it)
  }
  // gene reduction: per-wave shuffle, one entry per wave
#pragma unroll
  for (int off = 32; off > 0; off >>= 1) gene_acc += __shfl_xor(gene_acc, off);
  if (lane == 0) gene_part[blockIdx.x*4 + wave] = gene_acc * (1.f/128.f);
  // cell partials in bf16 (coalesced across t)
  unsigned short* dst = cell_partials + (size_t)blockIdx.x * NOUT;
#pragma unroll
  for (int u = 0; u < NH; ++u){
    __hip_bfloat16 bv = __float2bfloat16(cacc[u]);   // RNE
    unsigned short sv; __builtin_memcpy(&sv, &bv, 2);
    dst[u*256 + t] = sv;
  }
}

__global__ __launch_bounds__(256) void reduce1_kernel(const unsigned short* __restrict__ partials,
                                                      float* __restrict__ partial2){
  int o = (blockIdx.x % 68)*256 + threadIdx.x;   // 68*256 = NOUT exactly
  int c = blockIdx.x / 68;                       // NCHUNK chunks of 64 blocks
  int p0 = c*64, p1 = p0 + 64;
  float s0=0.f, s1=0.f, s2=0.f, s3=0.f;
  for (int p = p0; p < p1; p += 4){
    s0 += bf2f(partials[(size_t)(p+0)*NOUT + o]);
    s1 += bf2f(partials[(size_t)(p+1)*NOUT + o]);
    s2 += bf2f(partials[(size_t)(p+2)*NOUT + o]);
    s3 += bf2f(partials[(size_t)(p+3)*NOUT + o]);
  }
  partial2[(size_t)c*NOUT + o] = (s0+s1)+(s2+s3);
}

// Parallel 557KB -> 68KB reduction (68 blocks); removes the single-block
// serial global read that final_kernel was paying (~15-18us on one CU).
__global__ __launch_bounds__(256) void reduce2_kernel(const float* __restrict__ partial2,
                                                      float* __restrict__ G){
  int o = blockIdx.x*256 + threadIdx.x;          // grid 68
  float s = 0.f;
#pragma unroll
  for (int c = 0; c < NCHUNK; ++c) s += partial2[(size_t)c*NOUT + o];
  G[o] = s;
}

__device__ inline float getGs(const float* Gs, int f, int i, int j){
  int a = i < j ? i : j, c = i < j ? j : i;
  int k = a*16 - (a*(a-1))/2 + (c - a);          // linear index of (a,c), a<=c
  int hh = (k >= NH) ? 1 : 0;
  int u = k - hh*NH;
  return Gs[u*256 + hh*128 + f];
}

__global__ __launch_bounds__(256) void final_kernel(const float* __restrict__ G,
                                                    const float* __restrict__ gene_part,
                                                    int ngp, float* __restrict__ out){
  __shared__ float Gs[NOUT];           // 69.6 KB, loaded from 68KB Gbuf
  __shared__ float red[256];
  int t = threadIdx.x;
#pragma unroll
  for (int k = 0; k < NH; ++k) Gs[k*256 + t] = G[k*256 + t];
  __syncthreads();
  float v = 0.f;
  if (t < 128){
    int f = t;
    float d[16];
#pragma unroll
    for (int i = 0; i < 16; ++i) d[i] = getGs(Gs, f, i, i);
    float sum = 0.f;
#pragma unroll
    for (int i = 0; i < 16; ++i){
#pragma unroll
      for (int j = 0; j < 16; ++j){
        float sqd = d[i] + d[j] - 2.f*getGs(Gs, f, i, j);
        float dist = sqrtf(fmaxf(sqd, 0.f));
        sum += (((i < 8) == (j < 8)) ? -dist : dist);
      }
    }
    v = sum * (1.f/128.f) * (1.f/128.f);         // per-feature value / 128 features
  }
  float gp = 0.f;
  for (int idx = t; idx < ngp; idx += 256) gp += gene_part[idx];
  v += gp * (1.f/16384.f);                       // mean over clouds
  red[t] = v;
  __syncthreads();
  for (int s2 = 128; s2 > 0; s2 >>= 1){
    if (t < s2) red[t] += red[t + s2];
    __syncthreads();
  }
  if (t == 0) out[0] = red[0];
}

extern "C" void kernel_launch(void* const* d_in, const int* in_sizes, int n_in,
                              void* d_out, int out_size, void* d_ws, size_t ws_size,
                              hipStream_t stream){
  const float* X = (const float*)d_in[0];
  const float* Y = (const float*)d_in[1];
  float* out = (float*)d_out;

  float* wsf       = (float*)d_ws;
  float* gene_part = wsf;                            // NBLK*4 = 2048 floats
  float* Gbuf      = wsf + 2048;                     // NOUT floats
  float* partial2  = wsf + 2048 + NOUT;              // NCHUNK*NOUT floats
  unsigned short* partials =
      (unsigned short*)(wsf + 2048 + (1+NCHUNK)*NOUT);  // NBLK*NOUT bf16 (~17.8 MB)

  fused_kernel<<<NBLK, 256, 0, stream>>>(X, Y, partials, gene_part);
  reduce1_kernel<<<68*NCHUNK, 256, 0, stream>>>(partials, partial2);
  reduce2_kernel<<<68, 256, 0, stream>>>(partial2, Gbuf);
  final_kernel<<<1, 256, 0, stream>>>(Gbuf, gene_part, 4*NBLK, out);
}